// Round 1
// baseline (528.344 us; speedup 1.0000x reference)
//
#include <hip/hip_runtime.h>
#include <cstdint>
#include <cstddef>

typedef __bf16 bf16_t;
typedef __bf16 bf16x8 __attribute__((ext_vector_type(8)));
typedef float  f32x4  __attribute__((ext_vector_type(4)));

#define DHW   25088
#define SCALE 0.17677669529663687f  /* 32^-0.5 */

__device__ inline f32x4 mfma16(bf16x8 a, bf16x8 b, f32x4 c) {
  return __builtin_amdgcn_mfma_f32_16x16x32_bf16(a, b, c, 0, 0, 0);
}

// ---------------- K0: weight cast + rel-bias expansion ----------------
__global__ __launch_bounds__(256) void prep_kernel(
    const float* __restrict__ qkv_w, const float* __restrict__ proj_w,
    const float* __restrict__ fc1_w, const float* __restrict__ rel_bias,
    bf16_t* __restrict__ wq, bf16_t* __restrict__ wp, bf16_t* __restrict__ wf,
    float* __restrict__ biasexp)
{
  int idx = blockIdx.x * 256 + threadIdx.x;
  if (idx < 110592) { wq[idx] = (bf16_t)qkv_w[idx]; return; }
  idx -= 110592;
  if (idx < 36864) { wp[idx] = (bf16_t)proj_w[idx]; return; }
  idx -= 36864;
  if (idx < 36864) { wf[idx] = (bf16_t)fc1_w[idx]; return; }
  idx -= 36864;
  if (idx < 57624) {
    int h = idx / 9604, r = idx % 9604;
    int i = r / 98, j = r % 98;
    int di = i / 49 - j / 49 + 1;
    int hi = (i / 7) % 7 - (j / 7) % 7 + 6;
    int wi = i % 7 - j % 7 + 6;
    int rid = di * 169 + hi * 13 + wi;
    biasexp[h * 9604 + r] = rel_bias[rid * 6 + h];
  }
}

// ---------------- K1: LayerNorm + roll + window partition -------------
// output row orow = win*98+tok (window order); gathers from x with shift.
__global__ __launch_bounds__(256) void ln_kernel(
    const float* __restrict__ x, const float* __restrict__ gw,
    const float* __restrict__ bw_, bf16_t* __restrict__ xn)
{
  int orow = blockIdx.x * 4 + (threadIdx.x >> 6);
  int lane = threadIdx.x & 63;
  int win = orow / 98, tok = orow % 98;
  int b = win >> 8, wr = win & 255;
  int bd = wr >> 6, bh = (wr >> 3) & 7, bwi = wr & 7;
  int md = tok / 49, mh = (tok / 7) % 7, mw = tok % 7;
  int d = (bd * 2 + md + 1) & 7;
  int h = bh * 7 + mh + 3; if (h >= 56) h -= 56;
  int w = bwi * 7 + mw + 3; if (w >= 56) w -= 56;
  const float* xr = x + ((size_t)b * DHW + (size_t)((d * 56 + h) * 56 + w)) * 192;
  float v0 = xr[lane], v1 = xr[lane + 64], v2 = xr[lane + 128];
  float s = v0 + v1 + v2, sq = v0 * v0 + v1 * v1 + v2 * v2;
  #pragma unroll
  for (int off = 1; off < 64; off <<= 1) {
    s  += __shfl_xor(s,  off, 64);
    sq += __shfl_xor(sq, off, 64);
  }
  float mu = s * (1.0f / 192.0f);
  float var = sq * (1.0f / 192.0f) - mu * mu;
  float rstd = rsqrtf(var + 1e-5f);
  bf16_t* o = xn + (size_t)orow * 192;
  o[lane]       = (bf16_t)((v0 - mu) * rstd * gw[lane]       + bw_[lane]);
  o[lane + 64]  = (bf16_t)((v1 - mu) * rstd * gw[lane + 64]  + bw_[lane + 64]);
  o[lane + 128] = (bf16_t)((v2 - mu) * rstd * gw[lane + 128] + bw_[lane + 128]);
}

// ---------------- MFMA GEMM: C(M x Nout) = A(M x 192) @ W(Nout x 192)^T ----
// MODE 0: +bias -> bf16 plain store (QKV)
// MODE 1: +bias -> bf16 scatter through window-reverse + roll (proj)
// MODE 2: +bias -> exact GELU + fp32 residual -> f32 store (fc1)
template<int MODE>
__global__ __launch_bounds__(256) void gemm_kernel(
    const bf16_t* __restrict__ A, const bf16_t* __restrict__ W,
    const float* __restrict__ bias, int ntiles, int ncols,
    bf16_t* __restrict__ outb, float* __restrict__ outf,
    const float* __restrict__ resid)
{
  __shared__ __align__(16) bf16_t As[64][200];  // +8 pad: breaks 16-way bank conflict
  __shared__ __align__(16) bf16_t Bs[64][200];
  int tid = threadIdx.x;
  int nt = blockIdx.x % ntiles, mt = blockIdx.x / ntiles;
  int row0 = mt * 64, n0 = nt * 64;
  #pragma unroll
  for (int i = 0; i < 6; i++) {
    int c = tid + 256 * i;
    int r = c / 24, ck = c % 24;
    *(uint4*)&As[r][ck * 8] = *(const uint4*)(A + (size_t)(row0 + r) * 192 + ck * 8);
    *(uint4*)&Bs[r][ck * 8] = *(const uint4*)(W + (size_t)(n0 + r) * 192 + ck * 8);
  }
  __syncthreads();
  int wid = tid >> 6, lane = tid & 63;
  int wm = wid >> 1, wn = wid & 1;
  int g = lane >> 4, li = lane & 15;
  f32x4 acc[2][2] = {};
  #pragma unroll
  for (int ks = 0; ks < 6; ks++) {
    int ko = ks * 32 + g * 8;
    bf16x8 a0 = *(const bf16x8*)&As[wm * 32 + li][ko];
    bf16x8 a1 = *(const bf16x8*)&As[wm * 32 + 16 + li][ko];
    bf16x8 b0 = *(const bf16x8*)&Bs[wn * 32 + li][ko];
    bf16x8 b1 = *(const bf16x8*)&Bs[wn * 32 + 16 + li][ko];
    acc[0][0] = mfma16(a0, b0, acc[0][0]);
    acc[0][1] = mfma16(a0, b1, acc[0][1]);
    acc[1][0] = mfma16(a1, b0, acc[1][0]);
    acc[1][1] = mfma16(a1, b1, acc[1][1]);
  }
  #pragma unroll
  for (int mi = 0; mi < 2; mi++)
  #pragma unroll
  for (int ni = 0; ni < 2; ni++)
  #pragma unroll
  for (int v = 0; v < 4; v++) {
    int row = row0 + wm * 32 + mi * 16 + g * 4 + v;
    int col = n0 + wn * 32 + ni * 16 + li;
    float val = acc[mi][ni][v] + bias[col];
    if (MODE == 0) {
      outb[(size_t)row * ncols + col] = (bf16_t)val;
    } else if (MODE == 1) {
      int win = row / 98, tok = row % 98;
      int b = win >> 8, wr = win & 255;
      int bd = wr >> 6, bh = (wr >> 3) & 7, bwi = wr & 7;
      int md = tok / 49, mh = (tok / 7) % 7, mw = tok % 7;
      int d = (bd * 2 + md + 1) & 7;
      int hh = bh * 7 + mh + 3; if (hh >= 56) hh -= 56;
      int w2 = bwi * 7 + mw + 3; if (w2 >= 56) w2 -= 56;
      size_t grow = (size_t)b * DHW + (size_t)((d * 56 + hh) * 56 + w2);
      outb[grow * 192 + col] = (bf16_t)val;
    } else {
      float ge = 0.5f * val * (1.0f + erff(val * 0.70710678118654752f));
      size_t o = (size_t)row * 192 + col;
      outf[o] = resid[o] + ge;
    }
  }
}

// ---------------- Attention: one block = (window, head), 7 waves ------
__global__ __launch_bounds__(448) void attn_kernel(
    const bf16_t* __restrict__ qkv, const float* __restrict__ biasexp,
    const float* __restrict__ mask, bf16_t* __restrict__ ao)
{
  __shared__ __align__(16) bf16_t Qs[112][40];   // [tok][hd], +8 pad
  __shared__ __align__(16) bf16_t Ks[112][40];
  __shared__ __align__(16) bf16_t Vt[32][136];   // [hd][tok], padded to 128+8
  __shared__ __align__(16) bf16_t Ps[112][136];  // P in A-operand layout
  int bid = blockIdx.x;
  int h = bid % 6, win = bid / 6;
  int winb = win & 255;
  int tid = threadIdx.x;
  const bf16_t* base = qkv + (size_t)win * 98 * 576 + h * 32;
  // stage Q,K (16B chunks)
  for (int c = tid; c < 784; c += 448) {
    int cc = c < 392 ? c : c - 392;
    int tok = cc >> 2, part = cc & 3;
    const bf16_t* src = base + (c < 392 ? 0 : 192) + tok * 576 + part * 8;
    uint4 v = *(const uint4*)src;
    if (c < 392) *(uint4*)&Qs[tok][part * 8] = v;
    else         *(uint4*)&Ks[tok][part * 8] = v;
  }
  // stage V transposed
  for (int e = tid; e < 3136; e += 448) {
    int tok = e >> 5, hd = e & 31;
    Vt[hd][tok] = base[384 + tok * 576 + hd];
  }
  // zero Vt pad cols (blocks NaN*0 in PV)
  for (int e = tid; e < 1216; e += 448) {
    int r = e / 38, ci = 98 + e % 38;
    Vt[r][ci] = (bf16_t)0.0f;
  }
  __syncthreads();
  int wid = tid >> 6, lane = tid & 63;
  int mt = wid;                       // this wave's 16-row M strip
  int g = lane >> 4, li = lane & 15;
  bf16x8 af = *(const bf16x8*)&Qs[mt * 16 + li][g * 8];   // A-frag, K=32 in one go
  float logit[7][4];
  const float* bia = biasexp + h * 9604;
  const float* msk = mask + winb * 9604;
  #pragma unroll
  for (int nt2 = 0; nt2 < 7; nt2++) {
    bf16x8 bf = *(const bf16x8*)&Ks[nt2 * 16 + li][g * 8]; // B-frag = K^T
    f32x4 z = {};
    f32x4 S = mfma16(af, bf, z);
    int col = nt2 * 16 + li;
    #pragma unroll
    for (int v = 0; v < 4; v++) {
      int row = mt * 16 + g * 4 + v;
      logit[nt2][v] = (row < 98 && col < 98)
          ? S[v] * SCALE + bia[row * 98 + col] + msk[row * 98 + col]
          : -1e30f;
    }
  }
  // online row softmax: rows live in 16-lane groups (shfl_xor 1,2,4,8)
  #pragma unroll
  for (int v = 0; v < 4; v++) {
    float mx = logit[0][v];
    #pragma unroll
    for (int nt2 = 1; nt2 < 7; nt2++) mx = fmaxf(mx, logit[nt2][v]);
    #pragma unroll
    for (int off = 1; off < 16; off <<= 1) mx = fmaxf(mx, __shfl_xor(mx, off, 64));
    float se = 0.f;
    #pragma unroll
    for (int nt2 = 0; nt2 < 7; nt2++) {
      float p = __expf(logit[nt2][v] - mx);
      logit[nt2][v] = p; se += p;
    }
    #pragma unroll
    for (int off = 1; off < 16; off <<= 1) se += __shfl_xor(se, off, 64);
    float inv = 1.0f / se;
    int row = mt * 16 + g * 4 + v;
    #pragma unroll
    for (int nt2 = 0; nt2 < 7; nt2++)
      Ps[row][nt2 * 16 + li] = (bf16_t)(logit[nt2][v] * inv);
    Ps[row][112 + li] = (bf16_t)0.0f;   // zero cols 112..127
  }
  // PV: own-strip rows only -> no second barrier needed
  f32x4 o0 = {}, o1 = {};
  #pragma unroll
  for (int ks = 0; ks < 4; ks++) {
    int ko = ks * 32 + g * 8;
    bf16x8 pf = *(const bf16x8*)&Ps[mt * 16 + li][ko];
    bf16x8 v0 = *(const bf16x8*)&Vt[li][ko];
    bf16x8 v1 = *(const bf16x8*)&Vt[16 + li][ko];
    o0 = mfma16(pf, v0, o0);
    o1 = mfma16(pf, v1, o1);
  }
  bf16_t* aout = ao + (size_t)win * 98 * 192 + h * 32;
  #pragma unroll
  for (int v = 0; v < 4; v++) {
    int row = mt * 16 + g * 4 + v;
    if (row < 98) {
      aout[(size_t)row * 192 + li]      = (bf16_t)o0[v];
      aout[(size_t)row * 192 + 16 + li] = (bf16_t)o1[v];
    }
  }
}

// ---------------- launch ----------------
extern "C" void kernel_launch(void* const* d_in, const int* in_sizes, int n_in,
                              void* d_out, int out_size, void* d_ws, size_t ws_size,
                              hipStream_t stream) {
  (void)in_sizes; (void)n_in; (void)out_size; (void)ws_size;
  const float* x         = (const float*)d_in[0];
  const float* attn_mask = (const float*)d_in[1];
  const float* n1g       = (const float*)d_in[2];
  const float* n1b       = (const float*)d_in[3];
  const float* qkv_w     = (const float*)d_in[4];
  const float* qkv_b     = (const float*)d_in[5];
  const float* rel_bias  = (const float*)d_in[6];
  const float* proj_w    = (const float*)d_in[7];
  const float* proj_b    = (const float*)d_in[8];
  const float* fc1_w     = (const float*)d_in[9];
  const float* fc1_b     = (const float*)d_in[10];
  float* out = (float*)d_out;

  char* ws = (char*)d_ws;
  size_t off = 0;
  auto alloc = [&](size_t bytes) -> char* {
    char* p = ws + off;
    off += (bytes + 255) & ~(size_t)255;
    return p;
  };
  bf16_t* wq      = (bf16_t*)alloc(110592 * 2);
  bf16_t* wp      = (bf16_t*)alloc(36864 * 2);
  bf16_t* wf      = (bf16_t*)alloc(36864 * 2);
  float*  biasexp = (float*) alloc(57624 * 4);
  bf16_t* xn      = (bf16_t*)alloc((size_t)100352 * 192 * 2);
  bf16_t* qkv     = (bf16_t*)alloc((size_t)100352 * 576 * 2);
  bf16_t* y       = (bf16_t*)alloc((size_t)100352 * 192 * 2);
  bf16_t* ao      = xn;  // xn dead after QKV GEMM -> reuse for attention out

  prep_kernel<<<946, 256, 0, stream>>>(qkv_w, proj_w, fc1_w, rel_bias, wq, wp, wf, biasexp);
  ln_kernel<<<25088, 256, 0, stream>>>(x, n1g, n1b, xn);
  gemm_kernel<0><<<1568 * 9, 256, 0, stream>>>(xn, wq, qkv_b, 9, 576, qkv, nullptr, nullptr);
  attn_kernel<<<6144, 448, 0, stream>>>(qkv, biasexp, attn_mask, ao);
  gemm_kernel<1><<<1568 * 3, 256, 0, stream>>>(ao, wp, proj_b, 3, 192, y, nullptr, nullptr);
  gemm_kernel<2><<<1568 * 3, 256, 0, stream>>>(y, wf, fc1_b, 3, 192, nullptr, out, x);
}

// Round 2
// 450.394 us; speedup vs baseline: 1.1731x; 1.1731x over previous
//
#include <hip/hip_runtime.h>
#include <cstdint>
#include <cstddef>

typedef __bf16 bf16_t;
typedef __bf16 bf16x8 __attribute__((ext_vector_type(8)));
typedef float  f32x4  __attribute__((ext_vector_type(4)));

#define DHW   25088
#define SCALE 0.17677669529663687f  /* 32^-0.5 */

__device__ inline f32x4 mfma16(bf16x8 a, bf16x8 b, f32x4 c) {
  return __builtin_amdgcn_mfma_f32_16x16x32_bf16(a, b, c, 0, 0, 0);
}

// ---------------- K0a: weight cast ----------------
__global__ __launch_bounds__(256) void prep_kernel(
    const float* __restrict__ qkv_w, const float* __restrict__ proj_w,
    const float* __restrict__ fc1_w,
    bf16_t* __restrict__ wq, bf16_t* __restrict__ wp, bf16_t* __restrict__ wf)
{
  int idx = blockIdx.x * 256 + threadIdx.x;
  if (idx < 110592) { wq[idx] = (bf16_t)qkv_w[idx]; return; }
  idx -= 110592;
  if (idx < 36864) { wp[idx] = (bf16_t)proj_w[idx]; return; }
  idx -= 36864;
  if (idx < 36864) { wf[idx] = (bf16_t)fc1_w[idx]; }
}

// ---------------- K0b: fused bias+mask table in MFMA C-layout order ---
// bmr[winb(256)][h(6)][mt(7)][lane(64)][e(32)] bf16, e = nt2*4 + v
// value for (row = mt*16 + (lane>>4)*4 + v, col = (e>>2)*16 + (lane&15));
// padding entries get -1e30 (guard folded into table).
__global__ __launch_bounds__(256) void prep_bm_kernel(
    const float* __restrict__ rel_bias, const float* __restrict__ mask,
    bf16_t* __restrict__ bmr)
{
  int idx = blockIdx.x * 256 + threadIdx.x;   // exactly 22,020,096 threads
  int e    = idx & 31;
  int lane = (idx >> 5) & 63;
  int t    = idx >> 11;
  int mt   = t % 7;
  int wh   = t / 7;                 // winb*6 + h
  int winb = wh / 6, h = wh - winb * 6;
  int g = lane >> 4, li = lane & 15;
  int nt2 = e >> 2, v = e & 3;
  int row = mt * 16 + g * 4 + v;
  int col = nt2 * 16 + li;
  float val = -1e30f;
  if (row < 98 && col < 98 && nt2 < 7) {
    int di = row / 49 - col / 49 + 1;
    int hi = (row / 7) % 7 - (col / 7) % 7 + 6;
    int wi = row % 7 - col % 7 + 6;
    int rid = di * 169 + hi * 13 + wi;
    val = mask[winb * 9604 + row * 98 + col] + rel_bias[rid * 6 + h];
  }
  bmr[idx] = (bf16_t)val;
}

// ---------------- K1: LayerNorm + roll + window partition -------------
__global__ __launch_bounds__(256) void ln_kernel(
    const float* __restrict__ x, const float* __restrict__ gw,
    const float* __restrict__ bw_, bf16_t* __restrict__ xn)
{
  int orow = blockIdx.x * 4 + (threadIdx.x >> 6);
  int lane = threadIdx.x & 63;
  int win = orow / 98, tok = orow % 98;
  int b = win >> 8, wr = win & 255;
  int bd = wr >> 6, bh = (wr >> 3) & 7, bwi = wr & 7;
  int md = tok / 49, mh = (tok / 7) % 7, mw = tok % 7;
  int d = (bd * 2 + md + 1) & 7;
  int h = bh * 7 + mh + 3; if (h >= 56) h -= 56;
  int w = bwi * 7 + mw + 3; if (w >= 56) w -= 56;
  const float* xr = x + ((size_t)b * DHW + (size_t)((d * 56 + h) * 56 + w)) * 192;
  float v0 = xr[lane], v1 = xr[lane + 64], v2 = xr[lane + 128];
  float s = v0 + v1 + v2, sq = v0 * v0 + v1 * v1 + v2 * v2;
  #pragma unroll
  for (int off = 1; off < 64; off <<= 1) {
    s  += __shfl_xor(s,  off, 64);
    sq += __shfl_xor(sq, off, 64);
  }
  float mu = s * (1.0f / 192.0f);
  float var = sq * (1.0f / 192.0f) - mu * mu;
  float rstd = rsqrtf(var + 1e-5f);
  bf16_t* o = xn + (size_t)orow * 192;
  o[lane]       = (bf16_t)((v0 - mu) * rstd * gw[lane]       + bw_[lane]);
  o[lane + 64]  = (bf16_t)((v1 - mu) * rstd * gw[lane + 64]  + bw_[lane + 64]);
  o[lane + 128] = (bf16_t)((v2 - mu) * rstd * gw[lane + 128] + bw_[lane + 128]);
}

// ---------------- MFMA GEMM: C(M x Nout) = A(M x 192) @ W(Nout x 192)^T ----
template<int MODE>
__global__ __launch_bounds__(256) void gemm_kernel(
    const bf16_t* __restrict__ A, const bf16_t* __restrict__ W,
    const float* __restrict__ bias, int ntiles, int ncols,
    bf16_t* __restrict__ outb, float* __restrict__ outf,
    const float* __restrict__ resid)
{
  __shared__ __align__(16) bf16_t As[64][200];
  __shared__ __align__(16) bf16_t Bs[64][200];
  int tid = threadIdx.x;
  int nt = blockIdx.x % ntiles, mt = blockIdx.x / ntiles;
  int row0 = mt * 64, n0 = nt * 64;
  #pragma unroll
  for (int i = 0; i < 6; i++) {
    int c = tid + 256 * i;
    int r = c / 24, ck = c % 24;
    *(uint4*)&As[r][ck * 8] = *(const uint4*)(A + (size_t)(row0 + r) * 192 + ck * 8);
    *(uint4*)&Bs[r][ck * 8] = *(const uint4*)(W + (size_t)(n0 + r) * 192 + ck * 8);
  }
  __syncthreads();
  int wid = tid >> 6, lane = tid & 63;
  int wm = wid >> 1, wn = wid & 1;
  int g = lane >> 4, li = lane & 15;
  f32x4 acc[2][2] = {};
  #pragma unroll
  for (int ks = 0; ks < 6; ks++) {
    int ko = ks * 32 + g * 8;
    bf16x8 a0 = *(const bf16x8*)&As[wm * 32 + li][ko];
    bf16x8 a1 = *(const bf16x8*)&As[wm * 32 + 16 + li][ko];
    bf16x8 b0 = *(const bf16x8*)&Bs[wn * 32 + li][ko];
    bf16x8 b1 = *(const bf16x8*)&Bs[wn * 32 + 16 + li][ko];
    acc[0][0] = mfma16(a0, b0, acc[0][0]);
    acc[0][1] = mfma16(a0, b1, acc[0][1]);
    acc[1][0] = mfma16(a1, b0, acc[1][0]);
    acc[1][1] = mfma16(a1, b1, acc[1][1]);
  }
  #pragma unroll
  for (int mi = 0; mi < 2; mi++)
  #pragma unroll
  for (int ni = 0; ni < 2; ni++)
  #pragma unroll
  for (int v = 0; v < 4; v++) {
    int row = row0 + wm * 32 + mi * 16 + g * 4 + v;
    int col = n0 + wn * 32 + ni * 16 + li;
    float val = acc[mi][ni][v] + bias[col];
    if (MODE == 0) {
      outb[(size_t)row * ncols + col] = (bf16_t)val;
    } else if (MODE == 1) {
      int win = row / 98, tok = row % 98;
      int b = win >> 8, wr = win & 255;
      int bd = wr >> 6, bh = (wr >> 3) & 7, bwi = wr & 7;
      int md = tok / 49, mh = (tok / 7) % 7, mw = tok % 7;
      int d = (bd * 2 + md + 1) & 7;
      int hh = bh * 7 + mh + 3; if (hh >= 56) hh -= 56;
      int w2 = bwi * 7 + mw + 3; if (w2 >= 56) w2 -= 56;
      size_t grow = (size_t)b * DHW + (size_t)((d * 56 + hh) * 56 + w2);
      outb[grow * 192 + col] = (bf16_t)val;
    } else {
      float ge = 0.5f * val * (1.0f + erff(val * 0.70710678118654752f));
      size_t o = (size_t)row * 192 + col;
      outf[o] = resid[o] + ge;
    }
  }
}

// ---------------- Attention: one block = (window, head), 7 waves ------
// LDS: U = Qs[112][40] ++ Ks[112][40] (17,920 B), overlaid by Ps[112][136]
// (30,464 B) after the logit phase; Vt[32][136] separate (8,704 B).
// Total 39,168 B -> 4 blocks/CU by LDS; launch_bounds caps VGPR for >=6 waves/EU.
__global__ __launch_bounds__(448, 6) void attn_kernel(
    const bf16_t* __restrict__ qkv, const bf16_t* __restrict__ bmr,
    bf16_t* __restrict__ ao)
{
  __shared__ __align__(16) bf16_t U[15232];      // Qs/Ks then Ps
  __shared__ __align__(16) bf16_t Vt[32][136];
  int bid = blockIdx.x;
  int h = bid % 6, win = bid / 6;
  int winb = win & 255;
  int tid = threadIdx.x;
  int wid = tid >> 6, lane = tid & 63;
  int mt = wid, g = lane >> 4, li = lane & 15;

  // issue bias+mask fragment loads early (coalesced 64B/lane)
  const bf16_t* bmp = bmr + ((((size_t)(winb * 6 + h)) * 7 + mt) * 64 + lane) * 32;
  bf16x8 bm0 = *(const bf16x8*)(bmp);
  bf16x8 bm1 = *(const bf16x8*)(bmp + 8);
  bf16x8 bm2 = *(const bf16x8*)(bmp + 16);
  bf16x8 bm3 = *(const bf16x8*)(bmp + 24);

  const bf16_t* base = qkv + (size_t)win * 98 * 576 + h * 32;
  #define QS(r, c) U[(r) * 40 + (c)]
  #define KS(r, c) U[4480 + (r) * 40 + (c)]
  #define PS(r, c) U[(r) * 136 + (c)]
  // stage Q,K (16B chunks, coalesced)
  for (int c = tid; c < 784; c += 448) {
    int cc = c < 392 ? c : c - 392;
    int tok = cc >> 2, part = cc & 3;
    uint4 u = *(const uint4*)(base + (c < 392 ? 0 : 192) + tok * 576 + part * 8);
    if (c < 392) *(uint4*)&QS(tok, part * 8) = u;
    else         *(uint4*)&KS(tok, part * 8) = u;
  }
  // zero Q/K pad rows 98..111 (S on pads must be finite: guard lives in bmr)
  if (tid < 112) {
    uint4 z = {0, 0, 0, 0};
    int a = tid >> 6;            // 0: Qs, 1: Ks  (56 chunks each)
    int r = 98 + ((tid & 63) >> 2), part = tid & 3;
    if (r < 112) {
      if (a == 0) *(uint4*)&QS(r, part * 8) = z;
      else        *(uint4*)&KS(r, part * 8) = z;
    }
  }
  // stage V transposed (b128 global, b16 LDS writes)
  if (tid < 392) {
    int tok = tid >> 2, part = tid & 3;
    bf16x8 u = *(const bf16x8*)(base + 384 + tok * 576 + part * 8);
    #pragma unroll
    for (int j = 0; j < 8; j++) Vt[part * 8 + j][tok] = u[j];
  }
  // zero Vt cols 98..127 (read by PV; p there is 0 but must not be NaN)
  for (int e2 = tid; e2 < 960; e2 += 448) {
    int r = e2 / 30, ci = 98 + e2 % 30;
    Vt[r][ci] = (bf16_t)0.0f;
  }
  __syncthreads();

  bf16x8 af = *(const bf16x8*)&QS(mt * 16 + li, g * 8);
  float logit[7][4];
  #pragma unroll
  for (int nt2 = 0; nt2 < 7; nt2++) {
    bf16x8 bfr = *(const bf16x8*)&KS(nt2 * 16 + li, g * 8);
    f32x4 z = {};
    f32x4 S = mfma16(af, bfr, z);
    #pragma unroll
    for (int v = 0; v < 4; v++) {
      int e = nt2 * 4 + v;  // compile-time after unroll
      float bmv = (e < 8) ? (float)bm0[e] : (e < 16) ? (float)bm1[e - 8]
                : (e < 24) ? (float)bm2[e - 16] : (float)bm3[e - 24];
      logit[nt2][v] = S[v] * SCALE + bmv;
    }
  }
  __syncthreads();   // all waves done reading Qs/Ks -> Ps may overlay

  // row softmax (rows live in 16-lane groups)
  #pragma unroll
  for (int v = 0; v < 4; v++) {
    float mx = logit[0][v];
    #pragma unroll
    for (int nt2 = 1; nt2 < 7; nt2++) mx = fmaxf(mx, logit[nt2][v]);
    #pragma unroll
    for (int off = 1; off < 16; off <<= 1) mx = fmaxf(mx, __shfl_xor(mx, off, 64));
    float se = 0.f;
    #pragma unroll
    for (int nt2 = 0; nt2 < 7; nt2++) {
      float p = __expf(logit[nt2][v] - mx);
      logit[nt2][v] = p; se += p;
    }
    #pragma unroll
    for (int off = 1; off < 16; off <<= 1) se += __shfl_xor(se, off, 64);
    float inv = 1.0f / se;
    int row = mt * 16 + g * 4 + v;
    #pragma unroll
    for (int nt2 = 0; nt2 < 7; nt2++)
      PS(row, nt2 * 16 + li) = (bf16_t)(logit[nt2][v] * inv);
    PS(row, 112 + li) = (bf16_t)0.0f;   // zero K-pad cols 112..127
  }
  // PV: each wave reads only its own strip rows -> in-wave ordering suffices
  f32x4 o0 = {}, o1 = {};
  #pragma unroll
  for (int ks = 0; ks < 4; ks++) {
    int ko = ks * 32 + g * 8;
    bf16x8 pf = *(const bf16x8*)&PS(mt * 16 + li, ko);
    bf16x8 v0 = *(const bf16x8*)&Vt[li][ko];
    bf16x8 v1 = *(const bf16x8*)&Vt[16 + li][ko];
    o0 = mfma16(pf, v0, o0);
    o1 = mfma16(pf, v1, o1);
  }
  bf16_t* aout = ao + (size_t)win * 98 * 192 + h * 32;
  #pragma unroll
  for (int v = 0; v < 4; v++) {
    int row = mt * 16 + g * 4 + v;
    if (row < 98) {
      aout[(size_t)row * 192 + li]      = (bf16_t)o0[v];
      aout[(size_t)row * 192 + 16 + li] = (bf16_t)o1[v];
    }
  }
  #undef QS
  #undef KS
  #undef PS
}

// ---------------- launch ----------------
extern "C" void kernel_launch(void* const* d_in, const int* in_sizes, int n_in,
                              void* d_out, int out_size, void* d_ws, size_t ws_size,
                              hipStream_t stream) {
  (void)in_sizes; (void)n_in; (void)out_size; (void)ws_size;
  const float* x         = (const float*)d_in[0];
  const float* attn_mask = (const float*)d_in[1];
  const float* n1g       = (const float*)d_in[2];
  const float* n1b       = (const float*)d_in[3];
  const float* qkv_w     = (const float*)d_in[4];
  const float* qkv_b     = (const float*)d_in[5];
  const float* rel_bias  = (const float*)d_in[6];
  const float* proj_w    = (const float*)d_in[7];
  const float* proj_b    = (const float*)d_in[8];
  const float* fc1_w     = (const float*)d_in[9];
  const float* fc1_b     = (const float*)d_in[10];
  float* out = (float*)d_out;

  char* ws = (char*)d_ws;
  size_t off = 0;
  auto alloc = [&](size_t bytes) -> char* {
    char* p = ws + off;
    off += (bytes + 255) & ~(size_t)255;
    return p;
  };
  bf16_t* wq  = (bf16_t*)alloc(110592 * 2);
  bf16_t* wp  = (bf16_t*)alloc(36864 * 2);
  bf16_t* wf  = (bf16_t*)alloc(36864 * 2);
  bf16_t* bmr = (bf16_t*)alloc((size_t)22020096 * 2);
  bf16_t* xn  = (bf16_t*)alloc((size_t)100352 * 192 * 2);
  bf16_t* qkv = (bf16_t*)alloc((size_t)100352 * 576 * 2);
  bf16_t* y   = (bf16_t*)alloc((size_t)100352 * 192 * 2);
  bf16_t* ao  = xn;  // xn dead after QKV GEMM

  prep_kernel<<<720, 256, 0, stream>>>(qkv_w, proj_w, fc1_w, wq, wp, wf);
  prep_bm_kernel<<<86016, 256, 0, stream>>>(rel_bias, attn_mask, bmr);
  ln_kernel<<<25088, 256, 0, stream>>>(x, n1g, n1b, xn);
  gemm_kernel<0><<<1568 * 9, 256, 0, stream>>>(xn, wq, qkv_b, 9, 576, qkv, nullptr, nullptr);
  attn_kernel<<<6144, 448, 0, stream>>>(qkv, bmr, ao);
  gemm_kernel<1><<<1568 * 3, 256, 0, stream>>>(ao, wp, proj_b, 3, 192, y, nullptr, nullptr);
  gemm_kernel<2><<<1568 * 3, 256, 0, stream>>>(y, wf, fc1_b, 3, 192, nullptr, out, x);
}

// Round 3
// 423.874 us; speedup vs baseline: 1.2465x; 1.0626x over previous
//
#include <hip/hip_runtime.h>
#include <cstdint>
#include <cstddef>

typedef __bf16 bf16_t;
typedef __bf16 bf16x8 __attribute__((ext_vector_type(8)));
typedef float  f32x4  __attribute__((ext_vector_type(4)));

#define DHW   25088
#define SCALE 0.17677669529663687f  /* 32^-0.5 */

__device__ inline f32x4 mfma16(bf16x8 a, bf16x8 b, f32x4 c) {
  return __builtin_amdgcn_mfma_f32_16x16x32_bf16(a, b, c, 0, 0, 0);
}

// window-order row -> global (rolled) token row (shared by lnqkv gather & pf scatter)
__device__ inline size_t wrow_to_grow(int orow) {
  int win = orow / 98, tok = orow % 98;
  int b = win >> 8, wr = win & 255;
  int bd = wr >> 6, bh = (wr >> 3) & 7, bwi = wr & 7;
  int md = tok / 49, mh = (tok / 7) % 7, mw = tok % 7;
  int d = (bd * 2 + md + 1) & 7;
  int h = bh * 7 + mh + 3; if (h >= 56) h -= 56;
  int w = bwi * 7 + mw + 3; if (w >= 56) w -= 56;
  return (size_t)b * DHW + (size_t)((d * 56 + h) * 56 + w);
}

// ---------------- K0a: weight cast ----------------
__global__ __launch_bounds__(256) void prep_kernel(
    const float* __restrict__ qkv_w, const float* __restrict__ proj_w,
    const float* __restrict__ fc1_w,
    bf16_t* __restrict__ wq, bf16_t* __restrict__ wp, bf16_t* __restrict__ wf)
{
  int idx = blockIdx.x * 256 + threadIdx.x;
  if (idx < 110592) { wq[idx] = (bf16_t)qkv_w[idx]; return; }
  idx -= 110592;
  if (idx < 36864) { wp[idx] = (bf16_t)proj_w[idx]; return; }
  idx -= 36864;
  if (idx < 36864) { wf[idx] = (bf16_t)fc1_w[idx]; }
}

// ---------------- K0b: bias+mask table, 8 window-types, MFMA C-layout -
// Only 8 distinct masks exist: boundary-or-not per axis. 1.4 MB -> L2-resident.
// bmr[type(8)][h(6)][mt(7)][lane(64)][e(32)], e = nt2*4 + v; pad entries -1e30.
__global__ __launch_bounds__(256) void prep_bm_kernel(
    const float* __restrict__ rel_bias, const float* __restrict__ mask,
    bf16_t* __restrict__ bmr)
{
  int idx = blockIdx.x * 256 + threadIdx.x;   // exactly 688,128 threads
  int e    = idx & 31;
  int lane = (idx >> 5) & 63;
  int t2   = idx >> 11;
  int mt   = t2 % 7;
  int wh   = t2 / 7;
  int type = wh / 6, h = wh - type * 6;
  int winb = ((type & 4) ? 3 : 0) * 64 + ((type & 2) ? 7 : 0) * 8 + ((type & 1) ? 7 : 0);
  int g = lane >> 4, li = lane & 15;
  int nt2 = e >> 2, v = e & 3;
  int row = mt * 16 + g * 4 + v;
  int col = nt2 * 16 + li;
  float val = -1e30f;
  if (row < 98 && col < 98 && nt2 < 7) {
    int di = row / 49 - col / 49 + 1;
    int hi = (row / 7) % 7 - (col / 7) % 7 + 6;
    int wi = row % 7 - col % 7 + 6;
    int rid = di * 169 + hi * 13 + wi;
    val = mask[winb * 9604 + row * 98 + col] + rel_bias[rid * 6 + h];
  }
  bmr[idx] = (bf16_t)val;
}

// ---------------- K1: fused LayerNorm+roll+partition + QKV GEMM -------
// One block per 64-row M-tile; loops 9 W-tiles (L2-resident) with VGPR
// prefetch; A-fragments register-resident across all 9 tiles.
__global__ __launch_bounds__(256, 3) void lnqkv_kernel(
    const float* __restrict__ x, const float* __restrict__ gw,
    const float* __restrict__ bw_, const bf16_t* __restrict__ wq,
    const float* __restrict__ qkv_b, bf16_t* __restrict__ qkv)
{
  __shared__ __align__(16) bf16_t As[64][200];
  __shared__ __align__(16) bf16_t Bs[64][200];
  __shared__ float gws[192], bws[192], bias[576];
  int tid = threadIdx.x;
  int row0 = blockIdx.x * 64;
  if (tid < 192) { gws[tid] = gw[tid]; bws[tid] = bw_[tid]; }
  for (int c = tid; c < 576; c += 256) bias[c] = qkv_b[c];

  // --- LN staging: 4 threads per row, 48 f32 each ---
  {
    int r = tid >> 2, part = tid & 3;
    size_t grow = wrow_to_grow(row0 + r);
    const float* xr = x + grow * 192 + part * 48;
    float v[48];
    #pragma unroll
    for (int i = 0; i < 12; i++) *(float4*)&v[i * 4] = *(const float4*)(xr + i * 4);
    float s = 0.f, sq = 0.f;
    #pragma unroll
    for (int i = 0; i < 48; i++) { s += v[i]; sq += v[i] * v[i]; }
    s += __shfl_xor(s, 1, 64); sq += __shfl_xor(sq, 1, 64);
    s += __shfl_xor(s, 2, 64); sq += __shfl_xor(sq, 2, 64);
    float mu = s * (1.0f / 192.0f);
    float var = sq * (1.0f / 192.0f) - mu * mu;
    float rstd = rsqrtf(var + 1e-5f);
    __syncthreads();               // gws/bws visible
    bf16_t nb[48];
    #pragma unroll
    for (int i = 0; i < 48; i++) {
      int c = part * 48 + i;
      nb[i] = (bf16_t)((v[i] - mu) * rstd * gws[c] + bws[c]);
    }
    #pragma unroll
    for (int j = 0; j < 6; j++)
      *(bf16x8*)&As[r][part * 48 + j * 8] = *(bf16x8*)&nb[j * 8];
  }
  __syncthreads();

  int wid = tid >> 6, lane = tid & 63;
  int wm = wid >> 1, wn = wid & 1;
  int g = lane >> 4, li = lane & 15;
  // A-fragments: register-resident for all 9 N-tiles
  bf16x8 afr[2][6];
  #pragma unroll
  for (int ks = 0; ks < 6; ks++) {
    afr[0][ks] = *(const bf16x8*)&As[wm * 32 + li][ks * 32 + g * 8];
    afr[1][ks] = *(const bf16x8*)&As[wm * 32 + 16 + li][ks * 32 + g * 8];
  }

  uint4 st[6];
  #pragma unroll
  for (int i = 0; i < 6; i++) {
    int c = tid + 256 * i; int rr = c / 24, ck = c % 24;
    st[i] = *(const uint4*)(wq + (size_t)rr * 192 + ck * 8);
  }
  for (int nt = 0; nt < 9; nt++) {
    __syncthreads();               // prev-iter Bs readers done
    #pragma unroll
    for (int i = 0; i < 6; i++) {
      int c = tid + 256 * i; int rr = c / 24, ck = c % 24;
      *(uint4*)&Bs[rr][ck * 8] = st[i];
    }
    __syncthreads();               // Bs staged
    if (nt < 8) {
      #pragma unroll
      for (int i = 0; i < 6; i++) {
        int c = tid + 256 * i; int rr = c / 24, ck = c % 24;
        st[i] = *(const uint4*)(wq + (size_t)(nt + 1) * 12288 + (size_t)rr * 192 + ck * 8);
      }
    }
    f32x4 acc[2][2] = {};
    #pragma unroll
    for (int ks = 0; ks < 6; ks++) {
      int ko = ks * 32 + g * 8;
      bf16x8 b0 = *(const bf16x8*)&Bs[wn * 32 + li][ko];
      bf16x8 b1 = *(const bf16x8*)&Bs[wn * 32 + 16 + li][ko];
      acc[0][0] = mfma16(afr[0][ks], b0, acc[0][0]);
      acc[0][1] = mfma16(afr[0][ks], b1, acc[0][1]);
      acc[1][0] = mfma16(afr[1][ks], b0, acc[1][0]);
      acc[1][1] = mfma16(afr[1][ks], b1, acc[1][1]);
    }
    #pragma unroll
    for (int mi = 0; mi < 2; mi++)
    #pragma unroll
    for (int ni = 0; ni < 2; ni++)
    #pragma unroll
    for (int v = 0; v < 4; v++) {
      int row = row0 + wm * 32 + mi * 16 + g * 4 + v;
      int col = nt * 64 + wn * 32 + ni * 16 + li;
      qkv[(size_t)row * 576 + col] = (bf16_t)(acc[mi][ni][v] + bias[col]);
    }
  }
}

// ---------------- K2: attention, one block = (window, head), 7 waves --
__global__ __launch_bounds__(448, 6) void attn_kernel(
    const bf16_t* __restrict__ qkv, const bf16_t* __restrict__ bmr,
    bf16_t* __restrict__ ao)
{
  __shared__ __align__(16) bf16_t U[15232];      // Qs/Ks then Ps overlay
  __shared__ __align__(16) bf16_t Vt[32][136];
  int bid = blockIdx.x;
  int h = bid % 6, win = bid / 6;
  int winb = win & 255;
  int type = (((winb >> 6) == 3) ? 4 : 0) | ((((winb >> 3) & 7) == 7) ? 2 : 0)
           | (((winb & 7) == 7) ? 1 : 0);
  int tid = threadIdx.x;
  int wid = tid >> 6, lane = tid & 63;
  int mt = wid, g = lane >> 4, li = lane & 15;

  const bf16_t* bmp = bmr + ((((size_t)(type * 6 + h)) * 7 + mt) * 64 + lane) * 32;
  bf16x8 bm0 = *(const bf16x8*)(bmp);
  bf16x8 bm1 = *(const bf16x8*)(bmp + 8);
  bf16x8 bm2 = *(const bf16x8*)(bmp + 16);
  bf16x8 bm3 = *(const bf16x8*)(bmp + 24);

  const bf16_t* base = qkv + (size_t)win * 98 * 576 + h * 32;
  #define QS(r, c) U[(r) * 40 + (c)]
  #define KS(r, c) U[4480 + (r) * 40 + (c)]
  #define PS(r, c) U[(r) * 136 + (c)]
  for (int c = tid; c < 784; c += 448) {
    int cc = c < 392 ? c : c - 392;
    int tok = cc >> 2, part = cc & 3;
    uint4 u = *(const uint4*)(base + (c < 392 ? 0 : 192) + tok * 576 + part * 8);
    if (c < 392) *(uint4*)&QS(tok, part * 8) = u;
    else         *(uint4*)&KS(tok, part * 8) = u;
  }
  if (tid < 112) {
    uint4 z = {0, 0, 0, 0};
    int a = tid >> 6;
    int r = 98 + ((tid & 63) >> 2), part = tid & 3;
    if (r < 112) {
      if (a == 0) *(uint4*)&QS(r, part * 8) = z;
      else        *(uint4*)&KS(r, part * 8) = z;
    }
  }
  if (tid < 392) {
    int tok = tid >> 2, part = tid & 3;
    bf16x8 u = *(const bf16x8*)(base + 384 + tok * 576 + part * 8);
    #pragma unroll
    for (int j = 0; j < 8; j++) Vt[part * 8 + j][tok] = u[j];
  }
  for (int e2 = tid; e2 < 960; e2 += 448) {
    int r = e2 / 30, ci = 98 + e2 % 30;
    Vt[r][ci] = (bf16_t)0.0f;
  }
  __syncthreads();

  bf16x8 af = *(const bf16x8*)&QS(mt * 16 + li, g * 8);
  float logit[7][4];
  #pragma unroll
  for (int nt2 = 0; nt2 < 7; nt2++) {
    bf16x8 bfr = *(const bf16x8*)&KS(nt2 * 16 + li, g * 8);
    f32x4 z = {};
    f32x4 S = mfma16(af, bfr, z);
    #pragma unroll
    for (int v = 0; v < 4; v++) {
      int e = nt2 * 4 + v;
      float bmv = (e < 8) ? (float)bm0[e] : (e < 16) ? (float)bm1[e - 8]
                : (e < 24) ? (float)bm2[e - 16] : (float)bm3[e - 24];
      logit[nt2][v] = S[v] * SCALE + bmv;
    }
  }
  __syncthreads();   // Qs/Ks dead -> Ps overlay

  #pragma unroll
  for (int v = 0; v < 4; v++) {
    float mx = logit[0][v];
    #pragma unroll
    for (int nt2 = 1; nt2 < 7; nt2++) mx = fmaxf(mx, logit[nt2][v]);
    #pragma unroll
    for (int off = 1; off < 16; off <<= 1) mx = fmaxf(mx, __shfl_xor(mx, off, 64));
    float se = 0.f;
    #pragma unroll
    for (int nt2 = 0; nt2 < 7; nt2++) {
      float p = __expf(logit[nt2][v] - mx);
      logit[nt2][v] = p; se += p;
    }
    #pragma unroll
    for (int off = 1; off < 16; off <<= 1) se += __shfl_xor(se, off, 64);
    float inv = 1.0f / se;
    int row = mt * 16 + g * 4 + v;
    #pragma unroll
    for (int nt2 = 0; nt2 < 7; nt2++)
      PS(row, nt2 * 16 + li) = (bf16_t)(logit[nt2][v] * inv);
    PS(row, 112 + li) = (bf16_t)0.0f;
  }
  f32x4 o0 = {}, o1 = {};
  #pragma unroll
  for (int ks = 0; ks < 4; ks++) {
    int ko = ks * 32 + g * 8;
    bf16x8 pf = *(const bf16x8*)&PS(mt * 16 + li, ko);
    bf16x8 v0 = *(const bf16x8*)&Vt[li][ko];
    bf16x8 v1 = *(const bf16x8*)&Vt[16 + li][ko];
    o0 = mfma16(pf, v0, o0);
    o1 = mfma16(pf, v1, o1);
  }
  bf16_t* aout = ao + (size_t)win * 98 * 192 + h * 32;
  #pragma unroll
  for (int v = 0; v < 4; v++) {
    int row = mt * 16 + g * 4 + v;
    if (row < 98) {
      aout[(size_t)row * 192 + li]      = (bf16_t)o0[v];
      aout[(size_t)row * 192 + 16 + li] = (bf16_t)o1[v];
    }
  }
  #undef QS
  #undef KS
  #undef PS
}

// ---------------- K3: fused proj GEMM -> fc1 GEMM + GELU + residual ---
// C1 (proj out, bf16) overlays the dead A-tile LDS; GEMM2 reads it as A2.
__global__ __launch_bounds__(256, 3) void pf_kernel(
    const bf16_t* __restrict__ ao, const bf16_t* __restrict__ wp,
    const float* __restrict__ proj_b, const bf16_t* __restrict__ wf,
    const float* __restrict__ fc1_b, const float* __restrict__ x,
    float* __restrict__ out)
{
  __shared__ __align__(16) bf16_t As[64][200];   // ao tile, then C1 overlay
  __shared__ __align__(16) bf16_t Bs[64][200];
  __shared__ float pb[192], fb[192];
  int tid = threadIdx.x;
  int row0 = blockIdx.x * 64;
  if (tid < 192) { pb[tid] = proj_b[tid]; fb[tid] = fc1_b[tid]; }
  #pragma unroll
  for (int i = 0; i < 6; i++) {
    int c = tid + 256 * i; int rr = c / 24, ck = c % 24;
    *(uint4*)&As[rr][ck * 8] = *(const uint4*)(ao + (size_t)(row0 + rr) * 192 + ck * 8);
  }
  __syncthreads();

  int wid = tid >> 6, lane = tid & 63;
  int wm = wid >> 1, wn = wid & 1;
  int g = lane >> 4, li = lane & 15;
  bf16x8 afr[2][6];
  #pragma unroll
  for (int ks = 0; ks < 6; ks++) {
    afr[0][ks] = *(const bf16x8*)&As[wm * 32 + li][ks * 32 + g * 8];
    afr[1][ks] = *(const bf16x8*)&As[wm * 32 + 16 + li][ks * 32 + g * 8];
  }
  __syncthreads();   // all frag reads done -> As reusable as C1

  uint4 st[6];
  #pragma unroll
  for (int i = 0; i < 6; i++) {
    int c = tid + 256 * i; int rr = c / 24, ck = c % 24;
    st[i] = *(const uint4*)(wp + (size_t)rr * 192 + ck * 8);
  }
  // ---- phase 1: C1 = ao @ Wp^T + pb -> LDS (bf16) ----
  for (int nt = 0; nt < 3; nt++) {
    __syncthreads();
    #pragma unroll
    for (int i = 0; i < 6; i++) {
      int c = tid + 256 * i; int rr = c / 24, ck = c % 24;
      *(uint4*)&Bs[rr][ck * 8] = st[i];
    }
    __syncthreads();
    if (nt < 2) {
      #pragma unroll
      for (int i = 0; i < 6; i++) {
        int c = tid + 256 * i; int rr = c / 24, ck = c % 24;
        st[i] = *(const uint4*)(wp + (size_t)(nt + 1) * 12288 + (size_t)rr * 192 + ck * 8);
      }
    }
    f32x4 acc[2][2] = {};
    #pragma unroll
    for (int ks = 0; ks < 6; ks++) {
      int ko = ks * 32 + g * 8;
      bf16x8 b0 = *(const bf16x8*)&Bs[wn * 32 + li][ko];
      bf16x8 b1 = *(const bf16x8*)&Bs[wn * 32 + 16 + li][ko];
      acc[0][0] = mfma16(afr[0][ks], b0, acc[0][0]);
      acc[0][1] = mfma16(afr[0][ks], b1, acc[0][1]);
      acc[1][0] = mfma16(afr[1][ks], b0, acc[1][0]);
      acc[1][1] = mfma16(afr[1][ks], b1, acc[1][1]);
    }
    #pragma unroll
    for (int mi = 0; mi < 2; mi++)
    #pragma unroll
    for (int ni = 0; ni < 2; ni++)
    #pragma unroll
    for (int v = 0; v < 4; v++) {
      int rloc = wm * 32 + mi * 16 + g * 4 + v;
      int col = nt * 64 + wn * 32 + ni * 16 + li;
      As[rloc][col] = (bf16_t)(acc[mi][ni][v] + pb[col]);
    }
  }
  __syncthreads();   // C1 complete

  bf16x8 a2[2][6];
  #pragma unroll
  for (int ks = 0; ks < 6; ks++) {
    a2[0][ks] = *(const bf16x8*)&As[wm * 32 + li][ks * 32 + g * 8];
    a2[1][ks] = *(const bf16x8*)&As[wm * 32 + 16 + li][ks * 32 + g * 8];
  }
  #pragma unroll
  for (int i = 0; i < 6; i++) {
    int c = tid + 256 * i; int rr = c / 24, ck = c % 24;
    st[i] = *(const uint4*)(wf + (size_t)rr * 192 + ck * 8);
  }
  // ---- phase 2: out = GELU(C1 @ Wf^T + fb) + x (permuted residual) ----
  for (int nt = 0; nt < 3; nt++) {
    __syncthreads();
    #pragma unroll
    for (int i = 0; i < 6; i++) {
      int c = tid + 256 * i; int rr = c / 24, ck = c % 24;
      *(uint4*)&Bs[rr][ck * 8] = st[i];
    }
    __syncthreads();
    if (nt < 2) {
      #pragma unroll
      for (int i = 0; i < 6; i++) {
        int c = tid + 256 * i; int rr = c / 24, ck = c % 24;
        st[i] = *(const uint4*)(wf + (size_t)(nt + 1) * 12288 + (size_t)rr * 192 + ck * 8);
      }
    }
    f32x4 acc[2][2] = {};
    #pragma unroll
    for (int ks = 0; ks < 6; ks++) {
      int ko = ks * 32 + g * 8;
      bf16x8 b0 = *(const bf16x8*)&Bs[wn * 32 + li][ko];
      bf16x8 b1 = *(const bf16x8*)&Bs[wn * 32 + 16 + li][ko];
      acc[0][0] = mfma16(a2[0][ks], b0, acc[0][0]);
      acc[0][1] = mfma16(a2[0][ks], b1, acc[0][1]);
      acc[1][0] = mfma16(a2[1][ks], b0, acc[1][0]);
      acc[1][1] = mfma16(a2[1][ks], b1, acc[1][1]);
    }
    #pragma unroll
    for (int mi = 0; mi < 2; mi++)
    #pragma unroll
    for (int v = 0; v < 4; v++) {
      int rloc = wm * 32 + mi * 16 + g * 4 + v;
      size_t grow = wrow_to_grow(row0 + rloc);
      #pragma unroll
      for (int ni = 0; ni < 2; ni++) {
        int col = nt * 64 + wn * 32 + ni * 16 + li;
        float val = acc[mi][ni][v] + fb[col];
        float ge = 0.5f * val * (1.0f + erff(val * 0.70710678118654752f));
        size_t o = grow * 192 + col;
        out[o] = x[o] + ge;
      }
    }
  }
}

// ---------------- launch ----------------
extern "C" void kernel_launch(void* const* d_in, const int* in_sizes, int n_in,
                              void* d_out, int out_size, void* d_ws, size_t ws_size,
                              hipStream_t stream) {
  (void)in_sizes; (void)n_in; (void)out_size; (void)ws_size;
  const float* x         = (const float*)d_in[0];
  const float* attn_mask = (const float*)d_in[1];
  const float* n1g       = (const float*)d_in[2];
  const float* n1b       = (const float*)d_in[3];
  const float* qkv_w     = (const float*)d_in[4];
  const float* qkv_b     = (const float*)d_in[5];
  const float* rel_bias  = (const float*)d_in[6];
  const float* proj_w    = (const float*)d_in[7];
  const float* proj_b    = (const float*)d_in[8];
  const float* fc1_w     = (const float*)d_in[9];
  const float* fc1_b     = (const float*)d_in[10];
  float* out = (float*)d_out;

  char* ws = (char*)d_ws;
  size_t off = 0;
  auto alloc = [&](size_t bytes) -> char* {
    char* p = ws + off;
    off += (bytes + 255) & ~(size_t)255;
    return p;
  };
  bf16_t* wq  = (bf16_t*)alloc(110592 * 2);
  bf16_t* wp  = (bf16_t*)alloc(36864 * 2);
  bf16_t* wf  = (bf16_t*)alloc(36864 * 2);
  bf16_t* bmr = (bf16_t*)alloc((size_t)688128 * 2);
  bf16_t* qkv = (bf16_t*)alloc((size_t)100352 * 576 * 2);
  bf16_t* ao  = (bf16_t*)alloc((size_t)100352 * 192 * 2);

  prep_kernel<<<720, 256, 0, stream>>>(qkv_w, proj_w, fc1_w, wq, wp, wf);
  prep_bm_kernel<<<2688, 256, 0, stream>>>(rel_bias, attn_mask, bmr);
  lnqkv_kernel<<<1568, 256, 0, stream>>>(x, n1g, n1b, wq, qkv_b, qkv);
  attn_kernel<<<6144, 448, 0, stream>>>(qkv, bmr, ao);
  pf_kernel<<<1568, 256, 0, stream>>>(ao, wp, proj_b, wf, fc1_b, x, out);
}